// Round 6
// baseline (187.856 us; speedup 1.0000x reference)
//
#include <hip/hip_runtime.h>
#include <hip/hip_bf16.h>

#define B_   32
#define C_   16
#define H_   256
#define W_   256
#define HW_  65536      // H_*W_
#define HID_ 128
#define T_   8          // rows per block
#define NBLK_ (B_*H_/T_)   // 1024 blocks, 32 per image

typedef __attribute__((ext_vector_type(8)))  short bf16x8;
typedef __attribute__((ext_vector_type(4)))  float f32x4;
typedef __attribute__((ext_vector_type(16))) float f32x16;

__device__ __forceinline__ short f2bf(float f) {
    __hip_bfloat16 h = __float2bfloat16(f);
    return __builtin_bit_cast(short, h);
}

// hardware packed f32->bf16 RNE (no builtin on gfx950)
__device__ __forceinline__ int cvt_pk_bf16(float lo, float hi) {
    int r;
    asm("v_cvt_pk_bf16_f32 %0, %1, %2" : "=v"(r) : "v"(lo), "v"(hi));
    return r;
}

// ---------------- prep: fold w1 into per-o {A,B,C,b1} ------------------------
__global__ __launch_bounds__(128) void nca_prep(
    const float* __restrict__ w1, const float* __restrict__ b1,
    float4* __restrict__ coef4)
{
    int o = threadIdx.x;   // 0..127
    float A = 0.f, Bc = 0.f, Cc = 0.f;
    #pragma unroll
    for (int k = 0;  k < 16; ++k) A  += w1[o*48 + k];
    #pragma unroll
    for (int k = 16; k < 32; ++k) Bc += w1[o*48 + k];
    #pragma unroll
    for (int k = 32; k < 48; ++k) Cc += w1[o*48 + k];
    coef4[o] = make_float4(A, Bc, Cc, b1[o]);
}

// ---------------- fused: sum + sobel + MLP (BOTH layers MFMA) + update -------
// Block = 256 threads = one row; col = tid; T_=8 rows/block.
// Layer 1: h[128] = W1f[128x4]·(px,py,sc,1) via mfma_32x32x16_bf16 (K zero-pad).
// Layer 2: dx[16]  = W2[16x128]·h via mfma_16x16x32_bf16 (validated path).
// h-tile layout: per px, 8 units of 8B (4 consecutive hidden each), physical
// slot = u ^ (px&6)  -> 4-dword/bank floor for b64 writes AND b128 reads.
__global__ __launch_bounds__(256, 4) void nca_fused(
    const float* __restrict__ x, const int* __restrict__ mask,
    const float4* __restrict__ coef4, const float* __restrict__ w2,
    const float* __restrict__ b2,
    float* __restrict__ out, unsigned char* __restrict__ alpha)
{
    __shared__ float srow[T_+2][W_];   // 10 KB row sums
    __shared__ short hlds[4*2048];     // 16 KB: per-wave 4KB h-tile [64px][8 units]
    __shared__ short w2lds[4*64*8];    // 4 KB: layer-2 A-frags
    __shared__ short w1lds[4*32*4];    // 1 KB: [chunk][hid&31] -> {cA,cB,cC,b1} bf16
    __shared__ int   vlds[4*64*2];     // 2 KB: per-wave [64px] -> packed (px,py,sc,1)

    const int tid  = threadIdx.x;
    const int lane = tid & 63;
    const int widx = tid >> 6;
    const int col  = tid;              // owner column 0..255
    const int q  = lane & 15;          // 16x16 MFMA col lane
    const int g  = lane >> 4;          // 16x16 k-group
    const int cl = lane & 31;          // 32x32 col lane
    const int hi = lane >> 5;          // 32x32 half
    const int usw = cl & 6;            // h-tile unit swizzle key (== px&6)

    const int blk = blockIdx.x;
    const int b   = blk >> 5;          // 32 blocks per image
    const int r0  = (blk & 31) * T_;

    const float* xb = x    + (size_t)b * C_ * HW_;
    const int*   mb = mask + (size_t)b * HW_;
    float*       ob = (float*)out + (size_t)b * C_ * HW_;
    unsigned char* ab = alpha + (size_t)b * HW_;

    // ---- stage layer-2 A-frags: w2lds[kb*64+l] = bf16x8 ---------------------
    {
        const int kb = tid >> 6, l = tid & 63;
        const int qq = l & 15, gg = l >> 4;
        const float* wp = w2 + qq*HID_ + kb*32 + gg*8;
        bf16x8 a;
        #pragma unroll
        for (int j = 0; j < 8; ++j) a[j] = f2bf(wp[j]);
        *(bf16x8*)(w2lds + tid*8) = a;
    }
    // ---- stage layer-1 coef frags: w1lds[chunk*32+row] = {cA,cB,cC,b1} ------
    if (tid < 128) {
        const float4 cf = coef4[tid];            // chunk = tid>>5, row = tid&31
        *(int2*)(w1lds + tid*4) = make_int2(cvt_pk_bf16(cf.x, cf.y),
                                            cvt_pk_bf16(cf.z, cf.w));
    }

    // ---- prologue: sums for rows r0-1, r0; pipeline loads for r0+1 ----------
    float xnext[C_];
    {
        float s0 = 0.f;
        if (r0 > 0) {
            #pragma unroll
            for (int c = 0; c < C_; ++c) s0 += xb[c*HW_ + (r0-1)*W_ + col];
        }
        float s1 = 0.f;
        #pragma unroll
        for (int c = 0; c < C_; ++c) s1 += xb[c*HW_ + r0*W_ + col];
        #pragma unroll
        for (int c = 0; c < C_; ++c) xnext[c] = xb[c*HW_ + (r0+1)*W_ + col];
        srow[0][col] = s0;
        srow[1][col] = s1;
    }
    __syncthreads();   // w1lds/w2lds (and srow 0,1) visible

    // ---- hoist row-invariant fragments to registers -------------------------
    int2 a1[4];
    #pragma unroll
    for (int ch = 0; ch < 4; ++ch) a1[ch] = *(const int2*)(w1lds + (ch*32 + cl)*4);
    bf16x8 af2[4];
    #pragma unroll
    for (int kb = 0; kb < 4; ++kb) af2[kb] = *(const bf16x8*)(w2lds + (kb*64 + lane)*8);
    f32x4 bias;
    #pragma unroll
    for (int r = 0; r < 4; ++r) bias[r] = b2[g*4 + r];

    const bool lo = (lane < 32);
    int* vt = vlds + widx*128;                 // 64 px × 8B
    char* hb = (char*)(hlds + widx*2048);      // 4 KB h-tile

    f32x16 z16 = {0.f,0.f,0.f,0.f,0.f,0.f,0.f,0.f,
                  0.f,0.f,0.f,0.f,0.f,0.f,0.f,0.f};

    for (int r = 0; r < T_; ++r) {
        const int row = r0 + r;

        // finish pipelined sum for row+1 -> slot r+2
        {
            float s = 0.f;
            #pragma unroll
            for (int c = 0; c < C_; ++c) s += xnext[c];
            srow[r+2][col] = s;
        }
        __syncthreads();

        // issue next row's sum loads; zero below image bottom
        if (r < T_-1) {
            const int nr = r0 + r + 2;
            if (nr < H_) {
                #pragma unroll
                for (int c = 0; c < C_; ++c) xnext[c] = xb[c*HW_ + nr*W_ + col];
            } else {
                #pragma unroll
                for (int c = 0; c < C_; ++c) xnext[c] = 0.f;
            }
        }

        // prefetch mask for this wave's strip
        const int pstrip = row*W_ + (widx << 6);
        float mv[4];
        #pragma unroll
        for (int t = 0; t < 4; ++t) mv[t] = (float)mb[pstrip + t*16 + q];

        // ---- sobel on channel-sums from LDS ----
        const bool jm = col > 0, jp = col < W_-1;
        const float* sA = srow[r];
        const float* sB = srow[r+1];
        const float* sC = srow[r+2];
        float n00 = jm ? sA[col-1] : 0.f, n01 = sA[col], n02 = jp ? sA[col+1] : 0.f;
        float n10 = jm ? sB[col-1] : 0.f,                n12 = jp ? sB[col+1] : 0.f;
        float n20 = jm ? sC[col-1] : 0.f, n21 = sC[col], n22 = jp ? sC[col+1] : 0.f;
        float px = (n02 - n00) + 2.f*(n12 - n10) + (n22 - n20);
        float py = (n20 - n00) + 2.f*(n21 - n01) + (n22 - n02);
        float sc = sB[col];

        // ---- pack v = (px,py,sc,1) -> vtile ----
        *(int2*)(vt + lane*2) = make_int2(cvt_pk_bf16(px, py), cvt_pk_bf16(sc, 1.f));
        __builtin_amdgcn_wave_barrier();

        // v B-frags for the two 32-px groups (zero for k>=4 i.e. lanes>=32)
        int2 v0 = *(const int2*)(vt + cl*2);
        int2 v1 = *(const int2*)(vt + (32 + cl)*2);
        int4 b0i = make_int4(lo ? v0.x : 0, lo ? v0.y : 0, 0, 0);
        int4 b1i = make_int4(lo ? v1.x : 0, lo ? v1.y : 0, 0, 0);
        bf16x8 bf0 = __builtin_bit_cast(bf16x8, b0i);
        bf16x8 bf1 = __builtin_bit_cast(bf16x8, b1i);

        f32x4 acc[4];
        #pragma unroll
        for (int t = 0; t < 4; ++t) acc[t] = bias;

        #pragma unroll
        for (int ch = 0; ch < 4; ++ch) {
            // ---- layer 1: 32 hidden × 64 px via two 32x32x16 MFMAs ----
            int4 ai = make_int4(lo ? a1[ch].x : 0, lo ? a1[ch].y : 0, 0, 0);
            bf16x8 afr = __builtin_bit_cast(bf16x8, ai);
            f32x16 p0 = __builtin_amdgcn_mfma_f32_32x32x16_bf16(afr, bf0, z16, 0, 0, 0);
            f32x16 p1 = __builtin_amdgcn_mfma_f32_32x32x16_bf16(afr, bf1, z16, 0, 0, 0);

            // relu + pack + h-tile write: lane holds 16 hidden for px=G*32+cl,
            // rows 8m+4hi+w -> unit u=2m+hi (4 consecutive hidden), slot=u^usw
            #pragma unroll
            for (int m = 0; m < 4; ++m) {
                const int sl = ((2*m + hi) ^ usw) << 3;
                int2 d0 = make_int2(
                    cvt_pk_bf16(fmaxf(p0[4*m+0],0.f), fmaxf(p0[4*m+1],0.f)),
                    cvt_pk_bf16(fmaxf(p0[4*m+2],0.f), fmaxf(p0[4*m+3],0.f)));
                *(int2*)(hb + cl*64 + sl) = d0;
                int2 d1 = make_int2(
                    cvt_pk_bf16(fmaxf(p1[4*m+0],0.f), fmaxf(p1[4*m+1],0.f)),
                    cvt_pk_bf16(fmaxf(p1[4*m+2],0.f), fmaxf(p1[4*m+3],0.f)));
                *(int2*)(hb + (32+cl)*64 + sl) = d1;
            }
            __builtin_amdgcn_wave_barrier();

            // ---- layer 2: 4 groups of 16 px, B-frag slots {2g,2g+1}^swz ----
            #pragma unroll
            for (int t = 0; t < 4; ++t) {
                const int pp = t*16 + q;
                bf16x8 hbf = *(const bf16x8*)(hb + pp*64 + (((2*g) ^ (pp & 6)) << 3));
                acc[t] = __builtin_amdgcn_mfma_f32_16x16x32_bf16(
                             af2[ch], hbf, acc[t], 0, 0, 0);
            }
            __builtin_amdgcn_wave_barrier();
        }

        // ---- epilogue: direct stores, lane holds dx[ch=g*4+e][px=t*16+q] ----
        #pragma unroll
        for (int t = 0; t < 4; ++t) {
            const int pp = pstrip + t*16 + q;
            float xn3 = 0.f;
            #pragma unroll
            for (int e = 0; e < 4; ++e) {
                const int chn = g*4 + e;
                float xv = xb[chn*HW_ + pp];     // just-summed row -> cache hit
                float xn = fmaf(acc[t][e], mv[t], xv);
                ob[chn*HW_ + pp] = xn;
                if (chn == 3) xn3 = xn;
            }
            if (g == 0) ab[pp] = (xn3 > 0.1f) ? (unsigned char)1
                                              : (unsigned char)0;
        }
    }
}

// ---------------- k3: kill pixels with no alive neighbor ---------------------
__global__ __launch_bounds__(256) void nca_alive(
    const unsigned char* __restrict__ alpha, float* __restrict__ out)
{
    int t = blockIdx.x * blockDim.x + threadIdx.x;
    if (t >= B_*HW_) return;
    int b = t >> 16;
    int p = t & (HW_-1);
    int i = p >> 8;
    int j = p & (W_-1);
    const unsigned char* ab = alpha + (size_t)b * HW_;

    bool im = i > 0, ip = i < H_-1, jm = j > 0, jp = j < W_-1;
    int acc = ab[p];
    acc += jm ? ab[p-1] : 0;
    acc += jp ? ab[p+1] : 0;
    if (im) {
        acc += ab[p-W_];
        acc += jm ? ab[p-W_-1] : 0;
        acc += jp ? ab[p-W_+1] : 0;
    }
    if (ip) {
        acc += ab[p+W_];
        acc += jm ? ab[p+W_-1] : 0;
        acc += jp ? ab[p+W_+1] : 0;
    }
    if (acc == 0) {
        size_t base = (size_t)b * C_ * HW_ + p;
        #pragma unroll
        for (int c = 0; c < C_; ++c) out[base + (size_t)c * HW_] = 0.f;
    }
}

extern "C" void kernel_launch(void* const* d_in, const int* in_sizes, int n_in,
                              void* d_out, int out_size, void* d_ws, size_t ws_size,
                              hipStream_t stream)
{
    const float* x    = (const float*)d_in[0];
    const int*   mask = (const int*)d_in[1];
    const float* w1   = (const float*)d_in[2];
    const float* b1   = (const float*)d_in[3];
    const float* w2   = (const float*)d_in[4];
    const float* b2   = (const float*)d_in[5];
    float* out = (float*)d_out;

    // ws layout: alpha (B*HW bytes) | coef4 (128 float4)
    char* ws = (char*)d_ws;
    unsigned char* alpha = (unsigned char*)ws;
    float4*        coef4 = (float4*)(ws + (size_t)B_*HW_);

    nca_prep<<<1, 128, 0, stream>>>(w1, b1, coef4);

    nca_fused<<<NBLK_, 256, 0, stream>>>(x, mask, coef4, w2, b2, out, alpha);

    int n = B_*HW_;
    nca_alive<<<(n + 255)/256, 256, 0, stream>>>(alpha, out);
}

// Round 8
// 117.399 us; speedup vs baseline: 1.6002x; 1.6002x over previous
//
#include <hip/hip_runtime.h>
#include <hip/hip_fp16.h>

#define B_   32
#define C_   16
#define H_   256
#define W_   256
#define HW_  65536      // H_*W_
#define HID_ 128
#define T_   8          // rows per block
#define NBLK_ (B_*H_/T_)   // 1024 blocks, 32 per image

typedef __attribute__((ext_vector_type(8))) _Float16 f16x8;
typedef __attribute__((ext_vector_type(2))) _Float16 f16x2;
typedef __attribute__((ext_vector_type(4))) float    f32x4;

__device__ __forceinline__ int h2i(f16x2 h) { return __builtin_bit_cast(int, h); }
__device__ __forceinline__ f16x2 i2h(int i) { return __builtin_bit_cast(f16x2, i); }

__device__ __forceinline__ f16x2 pk(float a, float b) {
    f16x2 r; r.x = (_Float16)a; r.y = (_Float16)b; return r;
}

// ---------------- prep: fold w1 -> packed-f16 pair coefs ---------------------
// coefH[u] (u=0..63) = {pk(A[2u],A[2u+1]), pk(B..), pk(C..), pk(b1..)}
__global__ __launch_bounds__(128) void nca_prep(
    const float* __restrict__ w1, const float* __restrict__ b1,
    int4* __restrict__ coefH)
{
    __shared__ float4 tmp[128];
    int o = threadIdx.x;   // 0..127
    float A = 0.f, Bc = 0.f, Cc = 0.f;
    #pragma unroll
    for (int k = 0;  k < 16; ++k) A  += w1[o*48 + k];
    #pragma unroll
    for (int k = 16; k < 32; ++k) Bc += w1[o*48 + k];
    #pragma unroll
    for (int k = 32; k < 48; ++k) Cc += w1[o*48 + k];
    tmp[o] = make_float4(A, Bc, Cc, b1[o]);
    __syncthreads();
    if (o < 64) {
        float4 e = tmp[2*o], f = tmp[2*o+1];
        coefH[o] = make_int4(h2i(pk(e.x, f.x)), h2i(pk(e.y, f.y)),
                             h2i(pk(e.z, f.z)), h2i(pk(e.w, f.w)));
    }
}

// ---------------- fused: sum + sobel + f16-packed MLP1 + MFMA MLP2 + update --
// Block = 256 threads = one row; col = tid; T_=8 rows/block (r4-validated).
// Layer 1: packed v_pk_fma_f16 (2 hidden/inst), f16 pairs -> h-tile.
// Layer 2: mfma_f32_16x16x32_f16, A-frags = w2 (f16, LDS-staged, hoisted).
__global__ __launch_bounds__(256, 4) void nca_fused(
    const float* __restrict__ x, const int* __restrict__ mask,
    const int4* __restrict__ coefH, const float* __restrict__ w2,
    const float* __restrict__ b2,
    float* __restrict__ out, unsigned char* __restrict__ alpha)
{
    __shared__ float srow[T_+2][W_];   // 10 KB row sums
    __shared__ short hlds[4*2048];     // 16 KB: per-wave 4KB h-tile [64px][32 f16]
    __shared__ short w2lds[4*64*8];    // 4 KB: layer-2 A-frags (f16)

    const int tid  = threadIdx.x;
    const int lane = tid & 63;
    const int widx = tid >> 6;
    const int col  = tid;              // owner column 0..255
    const int q = lane & 15;           // MFMA col lane
    const int g = lane >> 4;           // MFMA k-group

    const int blk = blockIdx.x;
    const int b   = blk >> 5;          // 32 blocks per image
    const int r0  = (blk & 31) * T_;

    const float* xb = x    + (size_t)b * C_ * HW_;
    const int*   mb = mask + (size_t)b * HW_;
    float*       ob = (float*)out + (size_t)b * C_ * HW_;
    unsigned char* ab = alpha + (size_t)b * HW_;

    // ---- stage layer-2 A-frags (f16): w2lds[kb*64+l] -----------------------
    {
        const int kb = tid >> 6, l = tid & 63;
        const int qq = l & 15, gg = l >> 4;
        const float* wp = w2 + qq*HID_ + kb*32 + gg*8;
        f16x8 a;
        #pragma unroll
        for (int j = 0; j < 8; ++j) a[j] = (_Float16)wp[j];
        *(f16x8*)(w2lds + tid*8) = a;
    }

    // ---- prologue: sums for rows r0-1, r0; pipeline loads for r0+1 ----------
    float xnext[C_];
    {
        float s0 = 0.f;
        if (r0 > 0) {
            #pragma unroll
            for (int c = 0; c < C_; ++c) s0 += xb[c*HW_ + (r0-1)*W_ + col];
        }
        float s1 = 0.f;
        #pragma unroll
        for (int c = 0; c < C_; ++c) s1 += xb[c*HW_ + r0*W_ + col];
        #pragma unroll
        for (int c = 0; c < C_; ++c) xnext[c] = xb[c*HW_ + (r0+1)*W_ + col];
        srow[0][col] = s0;
        srow[1][col] = s1;
    }
    __syncthreads();   // w2lds + srow[0..1] visible to whole block

    // hoist row-invariant A-frags / bias
    f16x8 af2[4];
    #pragma unroll
    for (int kb = 0; kb < 4; ++kb) af2[kb] = *(const f16x8*)(w2lds + (kb*64 + lane)*8);
    f32x4 bias;
    #pragma unroll
    for (int r = 0; r < 4; ++r) bias[r] = b2[g*4 + r];

    const int wswz = (lane ^ (lane >> 2)) & 3;   // h-tile write swizzle
    const int rsw  = (q ^ (q >> 2)) & 3;         // h-tile read swizzle
    short* hw = hlds + widx*2048;                // 4KB per wave

    for (int r = 0; r < T_; ++r) {
        const int row = r0 + r;

        // finish pipelined sum for row+1 -> slot r+2
        {
            float s = 0.f;
            #pragma unroll
            for (int c = 0; c < C_; ++c) s += xnext[c];
            srow[r+2][col] = s;
        }
        __syncthreads();

        // issue next row's sum loads; zero below image bottom
        if (r < T_-1) {
            const int nr = r0 + r + 2;
            if (nr < H_) {
                #pragma unroll
                for (int c = 0; c < C_; ++c) xnext[c] = xb[c*HW_ + nr*W_ + col];
            } else {
                #pragma unroll
                for (int c = 0; c < C_; ++c) xnext[c] = 0.f;
            }
        }

        // prefetch mask for this wave's 64-px strip
        const int pstrip = row*W_ + (widx << 6);
        float mv[4];
        #pragma unroll
        for (int t = 0; t < 4; ++t) mv[t] = (float)mb[pstrip + t*16 + q];

        // ---- sobel on channel-sums from LDS ----
        const bool jm = col > 0, jp = col < W_-1;
        const float* sA = srow[r];
        const float* sB = srow[r+1];
        const float* sC = srow[r+2];
        float n00 = jm ? sA[col-1] : 0.f, n01 = sA[col], n02 = jp ? sA[col+1] : 0.f;
        float n10 = jm ? sB[col-1] : 0.f,                n12 = jp ? sB[col+1] : 0.f;
        float n20 = jm ? sC[col-1] : 0.f, n21 = sC[col], n22 = jp ? sC[col+1] : 0.f;
        float px = (n02 - n00) + 2.f*(n12 - n10) + (n22 - n20);
        float py = (n20 - n00) + 2.f*(n21 - n01) + (n22 - n02);
        float sc = sB[col];

        const f16x2 px2 = pk(px, px);
        const f16x2 py2 = pk(py, py);
        const f16x2 sc2 = pk(sc, sc);
        const f16x2 z2  = pk(0.f, 0.f);

        f32x4 acc[4];
        #pragma unroll
        for (int t = 0; t < 4; ++t) acc[t] = bias;

        #pragma unroll
        for (int kb = 0; kb < 4; ++kb) {
            // layer 1: chunk c = 8 hidden = 4 f16 pairs; coefH uniform -> s_load
            #pragma unroll
            for (int c = 0; c < 4; ++c) {
                int hd[4];
                #pragma unroll
                for (int u = 0; u < 4; ++u) {
                    const int4 cw = coefH[kb*16 + c*4 + u];
                    f16x2 h2 = __builtin_elementwise_fma(i2h(cw.x), px2,
                               __builtin_elementwise_fma(i2h(cw.y), py2,
                               __builtin_elementwise_fma(i2h(cw.z), sc2,
                                                         i2h(cw.w))));
                    h2 = __builtin_elementwise_max(h2, z2);
                    hd[u] = h2i(h2);
                }
                *(int4*)(hw + lane*32 + ((c ^ wswz) << 3)) =
                    make_int4(hd[0], hd[1], hd[2], hd[3]);
            }
            __builtin_amdgcn_wave_barrier();
            // layer 2: 4 groups of 16 px (validated fragment mapping)
            #pragma unroll
            for (int t = 0; t < 4; ++t) {
                const int pp = t*16 + q;
                f16x8 hbf = *(const f16x8*)(hw + pp*32 + (((g ^ rsw) & 3) << 3));
                acc[t] = __builtin_amdgcn_mfma_f32_16x16x32_f16(
                             af2[kb], hbf, acc[t], 0, 0, 0);
            }
            __builtin_amdgcn_wave_barrier();
        }

        // ---- epilogue: direct stores, lane holds dx[ch=g*4+e][px=t*16+q] ----
        #pragma unroll
        for (int t = 0; t < 4; ++t) {
            const int pp = pstrip + t*16 + q;
            float xn3 = 0.f;
            #pragma unroll
            for (int e = 0; e < 4; ++e) {
                const int chn = g*4 + e;
                float xv = xb[chn*HW_ + pp];     // just-summed row -> cache hit
                float xn = fmaf(acc[t][e], mv[t], xv);
                ob[chn*HW_ + pp] = xn;
                if (chn == 3) xn3 = xn;
            }
            if (g == 0) ab[pp] = (xn3 > 0.1f) ? (unsigned char)1
                                              : (unsigned char)0;
        }
    }
}

// ---------------- k3: kill pixels with no alive neighbor ---------------------
__global__ __launch_bounds__(256) void nca_alive(
    const unsigned char* __restrict__ alpha, float* __restrict__ out)
{
    int t = blockIdx.x * blockDim.x + threadIdx.x;
    if (t >= B_*HW_) return;
    int b = t >> 16;
    int p = t & (HW_-1);
    int i = p >> 8;
    int j = p & (W_-1);
    const unsigned char* ab = alpha + (size_t)b * HW_;

    bool im = i > 0, ip = i < H_-1, jm = j > 0, jp = j < W_-1;
    int acc = ab[p];
    acc += jm ? ab[p-1] : 0;
    acc += jp ? ab[p+1] : 0;
    if (im) {
        acc += ab[p-W_];
        acc += jm ? ab[p-W_-1] : 0;
        acc += jp ? ab[p-W_+1] : 0;
    }
    if (ip) {
        acc += ab[p+W_];
        acc += jm ? ab[p+W_-1] : 0;
        acc += jp ? ab[p+W_+1] : 0;
    }
    if (acc == 0) {
        size_t base = (size_t)b * C_ * HW_ + p;
        #pragma unroll
        for (int c = 0; c < C_; ++c) out[base + (size_t)c * HW_] = 0.f;
    }
}

extern "C" void kernel_launch(void* const* d_in, const int* in_sizes, int n_in,
                              void* d_out, int out_size, void* d_ws, size_t ws_size,
                              hipStream_t stream)
{
    const float* x    = (const float*)d_in[0];
    const int*   mask = (const int*)d_in[1];
    const float* w1   = (const float*)d_in[2];
    const float* b1   = (const float*)d_in[3];
    const float* w2   = (const float*)d_in[4];
    const float* b2   = (const float*)d_in[5];
    float* out = (float*)d_out;

    // ws layout: alpha (B*HW bytes) | coefH (64 × int4)
    char* ws = (char*)d_ws;
    unsigned char* alpha = (unsigned char*)ws;
    int4*          coefH = (int4*)(ws + (size_t)B_*HW_);

    nca_prep<<<1, 128, 0, stream>>>(w1, b1, coefH);

    nca_fused<<<NBLK_, 256, 0, stream>>>(x, mask, coefH, w2, b2, out, alpha);

    int n = B_*HW_;
    nca_alive<<<(n + 255)/256, 256, 0, stream>>>(alpha, out);
}

// Round 9
// 101.276 us; speedup vs baseline: 1.8549x; 1.1592x over previous
//
#include <hip/hip_runtime.h>
#include <hip/hip_fp16.h>

#define B_   32
#define C_   16
#define H_   256
#define W_   256
#define HW_  65536      // H_*W_
#define HID_ 128
#define T_   8          // rows per block
#define NBLK_ (B_*H_/T_)   // 1024 blocks, 32 per image

typedef __attribute__((ext_vector_type(8))) _Float16 f16x8;
typedef __attribute__((ext_vector_type(2))) _Float16 f16x2;
typedef __attribute__((ext_vector_type(4))) float    f32x4;

__device__ __forceinline__ int h2i(f16x2 h) { return __builtin_bit_cast(int, h); }
__device__ __forceinline__ f16x2 i2h(int i) { return __builtin_bit_cast(f16x2, i); }

__device__ __forceinline__ f16x2 pk(float a, float b) {
    f16x2 r; r.x = (_Float16)a; r.y = (_Float16)b; return r;
}

// ---------------- prep: fold w1 -> packed-f16 pair coefs ---------------------
// coefH[u] (u=0..63) = {pk(A[2u],A[2u+1]), pk(B..), pk(C..), pk(b1..)}
__global__ __launch_bounds__(128) void nca_prep(
    const float* __restrict__ w1, const float* __restrict__ b1,
    int4* __restrict__ coefH)
{
    __shared__ float4 tmp[128];
    int o = threadIdx.x;   // 0..127
    float A = 0.f, Bc = 0.f, Cc = 0.f;
    #pragma unroll
    for (int k = 0;  k < 16; ++k) A  += w1[o*48 + k];
    #pragma unroll
    for (int k = 16; k < 32; ++k) Bc += w1[o*48 + k];
    #pragma unroll
    for (int k = 32; k < 48; ++k) Cc += w1[o*48 + k];
    tmp[o] = make_float4(A, Bc, Cc, b1[o]);
    __syncthreads();
    if (o < 64) {
        float4 e = tmp[2*o], f = tmp[2*o+1];
        coefH[o] = make_int4(h2i(pk(e.x, f.x)), h2i(pk(e.y, f.y)),
                             h2i(pk(e.z, f.z)), h2i(pk(e.w, f.w)));
    }
}

// ---------------- fused: sum + sobel + f16-packed MLP1 + MFMA MLP2 + update --
// Block = 256 threads = one row; col = tid; T_=8 rows/block.
// Layer 1: packed v_pk_fma_f16 (2 hidden/inst), f16 pairs -> h-tile.
// Layer 2: mfma_f32_16x16x32_f16; A-frags hoisted from global w2 (L2-hot).
// launch_bounds(256,3): VGPR cap ~170 -> NO spill (r8's 64-cap spilled ~30MB).
__global__ __launch_bounds__(256, 3) void nca_fused(
    const float* __restrict__ x, const int* __restrict__ mask,
    const int4* __restrict__ coefH, const float* __restrict__ w2,
    const float* __restrict__ b2,
    float* __restrict__ out, unsigned char* __restrict__ alpha)
{
    __shared__ float srow[T_+2][W_];   // 10 KB row sums
    __shared__ short hlds[4*2048];     // 16 KB: per-wave 4KB h-tile [64px][32 f16]

    const int tid  = threadIdx.x;
    const int lane = tid & 63;
    const int widx = tid >> 6;
    const int col  = tid;              // owner column 0..255
    const int q = lane & 15;           // MFMA col lane
    const int g = lane >> 4;           // MFMA k-group

    const int blk = blockIdx.x;
    const int b   = blk >> 5;          // 32 blocks per image
    const int r0  = (blk & 31) * T_;

    const float* xb = x    + (size_t)b * C_ * HW_;
    const int*   mb = mask + (size_t)b * HW_;
    float*       ob = (float*)out + (size_t)b * C_ * HW_;
    unsigned char* ab = alpha + (size_t)b * HW_;

    // ---- hoist layer-2 A-frags straight from global (once; w2 is L2-hot) ---
    f16x8 af2[4];
    #pragma unroll
    for (int kb = 0; kb < 4; ++kb) {
        const float* wp = w2 + q*HID_ + kb*32 + g*8;
        f16x8 a;
        #pragma unroll
        for (int j = 0; j < 8; ++j) a[j] = (_Float16)wp[j];
        af2[kb] = a;
    }
    f32x4 bias;
    #pragma unroll
    for (int r = 0; r < 4; ++r) bias[r] = b2[g*4 + r];

    // ---- prologue: sums for rows r0-1, r0; pipeline loads for r0+1 ----------
    float xnext[C_];
    {
        float s0 = 0.f;
        if (r0 > 0) {
            #pragma unroll
            for (int c = 0; c < C_; ++c) s0 += xb[c*HW_ + (r0-1)*W_ + col];
        }
        float s1 = 0.f;
        #pragma unroll
        for (int c = 0; c < C_; ++c) s1 += xb[c*HW_ + r0*W_ + col];
        #pragma unroll
        for (int c = 0; c < C_; ++c) xnext[c] = xb[c*HW_ + (r0+1)*W_ + col];
        srow[0][col] = s0;
        srow[1][col] = s1;
    }

    const int wswz = (lane ^ (lane >> 2)) & 3;   // h-tile write swizzle
    const int rsw  = (q ^ (q >> 2)) & 3;         // h-tile read swizzle
    short* hw = hlds + widx*2048;                // 4KB per wave

    for (int r = 0; r < T_; ++r) {
        const int row = r0 + r;

        // finish pipelined sum for row+1 -> slot r+2
        {
            float s = 0.f;
            #pragma unroll
            for (int c = 0; c < C_; ++c) s += xnext[c];
            srow[r+2][col] = s;
        }
        __syncthreads();

        // issue next row's sum loads; zero below image bottom
        if (r < T_-1) {
            const int nr = r0 + r + 2;
            if (nr < H_) {
                #pragma unroll
                for (int c = 0; c < C_; ++c) xnext[c] = xb[c*HW_ + nr*W_ + col];
            } else {
                #pragma unroll
                for (int c = 0; c < C_; ++c) xnext[c] = 0.f;
            }
        }

        // prefetch mask for this wave's 64-px strip
        const int pstrip = row*W_ + (widx << 6);
        float mv[4];
        #pragma unroll
        for (int t = 0; t < 4; ++t) mv[t] = (float)mb[pstrip + t*16 + q];

        // ---- sobel on channel-sums from LDS ----
        const bool jm = col > 0, jp = col < W_-1;
        const float* sA = srow[r];
        const float* sB = srow[r+1];
        const float* sC = srow[r+2];
        float n00 = jm ? sA[col-1] : 0.f, n01 = sA[col], n02 = jp ? sA[col+1] : 0.f;
        float n10 = jm ? sB[col-1] : 0.f,                n12 = jp ? sB[col+1] : 0.f;
        float n20 = jm ? sC[col-1] : 0.f, n21 = sC[col], n22 = jp ? sC[col+1] : 0.f;
        float px = (n02 - n00) + 2.f*(n12 - n10) + (n22 - n20);
        float py = (n20 - n00) + 2.f*(n21 - n01) + (n22 - n02);
        float sc = sB[col];

        const f16x2 px2 = pk(px, px);
        const f16x2 py2 = pk(py, py);
        const f16x2 sc2 = pk(sc, sc);
        const f16x2 z2  = pk(0.f, 0.f);

        f32x4 acc[4];
        #pragma unroll
        for (int t = 0; t < 4; ++t) acc[t] = bias;

        #pragma unroll
        for (int kb = 0; kb < 4; ++kb) {
            // layer 1: chunk c = 8 hidden = 4 f16 pairs; coefH uniform -> s_load
            #pragma unroll
            for (int c = 0; c < 4; ++c) {
                int hd[4];
                #pragma unroll
                for (int u = 0; u < 4; ++u) {
                    const int4 cw = coefH[kb*16 + c*4 + u];
                    f16x2 h2 = __builtin_elementwise_fma(i2h(cw.x), px2,
                               __builtin_elementwise_fma(i2h(cw.y), py2,
                               __builtin_elementwise_fma(i2h(cw.z), sc2,
                                                         i2h(cw.w))));
                    h2 = __builtin_elementwise_max(h2, z2);
                    hd[u] = h2i(h2);
                }
                *(int4*)(hw + lane*32 + ((c ^ wswz) << 3)) =
                    make_int4(hd[0], hd[1], hd[2], hd[3]);
            }
            __builtin_amdgcn_wave_barrier();
            // layer 2: 4 groups of 16 px (validated fragment mapping)
            #pragma unroll
            for (int t = 0; t < 4; ++t) {
                const int pp = t*16 + q;
                f16x8 hbf = *(const f16x8*)(hw + pp*32 + (((g ^ rsw) & 3) << 3));
                acc[t] = __builtin_amdgcn_mfma_f32_16x16x32_f16(
                             af2[kb], hbf, acc[t], 0, 0, 0);
            }
            __builtin_amdgcn_wave_barrier();
        }

        // ---- epilogue: direct stores, lane holds dx[ch=g*4+e][px=t*16+q] ----
        #pragma unroll
        for (int t = 0; t < 4; ++t) {
            const int pp = pstrip + t*16 + q;
            float xn3 = 0.f;
            #pragma unroll
            for (int e = 0; e < 4; ++e) {
                const int chn = g*4 + e;
                float xv = xb[chn*HW_ + pp];     // just-summed row -> cache hit
                float xn = fmaf(acc[t][e], mv[t], xv);
                ob[chn*HW_ + pp] = xn;
                if (chn == 3) xn3 = xn;
            }
            if (g == 0) ab[pp] = (xn3 > 0.1f) ? (unsigned char)1
                                              : (unsigned char)0;
        }
    }
}

// ---------------- k3: kill pixels with no alive neighbor ---------------------
__global__ __launch_bounds__(256) void nca_alive(
    const unsigned char* __restrict__ alpha, float* __restrict__ out)
{
    int t = blockIdx.x * blockDim.x + threadIdx.x;
    if (t >= B_*HW_) return;
    int b = t >> 16;
    int p = t & (HW_-1);
    int i = p >> 8;
    int j = p & (W_-1);
    const unsigned char* ab = alpha + (size_t)b * HW_;

    bool im = i > 0, ip = i < H_-1, jm = j > 0, jp = j < W_-1;
    int acc = ab[p];
    acc += jm ? ab[p-1] : 0;
    acc += jp ? ab[p+1] : 0;
    if (im) {
        acc += ab[p-W_];
        acc += jm ? ab[p-W_-1] : 0;
        acc += jp ? ab[p-W_+1] : 0;
    }
    if (ip) {
        acc += ab[p+W_];
        acc += jm ? ab[p+W_-1] : 0;
        acc += jp ? ab[p+W_+1] : 0;
    }
    if (acc == 0) {
        size_t base = (size_t)b * C_ * HW_ + p;
        #pragma unroll
        for (int c = 0; c < C_; ++c) out[base + (size_t)c * HW_] = 0.f;
    }
}

extern "C" void kernel_launch(void* const* d_in, const int* in_sizes, int n_in,
                              void* d_out, int out_size, void* d_ws, size_t ws_size,
                              hipStream_t stream)
{
    const float* x    = (const float*)d_in[0];
    const int*   mask = (const int*)d_in[1];
    const float* w1   = (const float*)d_in[2];
    const float* b1   = (const float*)d_in[3];
    const float* w2   = (const float*)d_in[4];
    const float* b2   = (const float*)d_in[5];
    float* out = (float*)d_out;

    // ws layout: alpha (B*HW bytes) | coefH (64 × int4)
    char* ws = (char*)d_ws;
    unsigned char* alpha = (unsigned char*)ws;
    int4*          coefH = (int4*)(ws + (size_t)B_*HW_);

    nca_prep<<<1, 128, 0, stream>>>(w1, b1, coefH);

    nca_fused<<<NBLK_, 256, 0, stream>>>(x, mask, coefH, w2, b2, out, alpha);

    int n = B_*HW_;
    nca_alive<<<(n + 255)/256, 256, 0, stream>>>(alpha, out);
}